// Round 3
// baseline (94.417 us; speedup 1.0000x reference)
//
#include <hip/hip_runtime.h>
#include <math.h>

#define N 512
#define TILE 32

struct F3 { float x, y, z; };

__device__ __forceinline__ F3 f3sub(F3 a, F3 b) { return {a.x - b.x, a.y - b.y, a.z - b.z}; }
__device__ __forceinline__ F3 f3cross(F3 a, F3 b) {
    return {a.y * b.z - a.z * b.y, a.z * b.x - a.x * b.z, a.x * b.y - a.y * b.x};
}
__device__ __forceinline__ float f3dot(F3 a, F3 b) { return a.x * b.x + a.y * b.y + a.z * b.z; }

// Abramowitz-Stegun 4.4.45: asin(x) = pi/2 - sqrt(1-x)*poly3(x), x in [0,1], |err| <= 5e-5.
// Branch-free, 1 quarter-rate sqrt + 4 FMA vs libm asinf's ~40 instrs with branches.
__device__ __forceinline__ float fast_asinf(float x) {
    float ax = fabsf(x);
    float p = fmaf(ax, -0.0187293f, 0.0742610f);
    p = fmaf(ax, p, -0.2121144f);
    p = fmaf(ax, p, 1.5707288f);
    float r = 1.5707963267948966f - __builtin_sqrtf(1.0f - ax) * p;
    return copysignf(r, x);
}

// Writhe contribution for segment pair using atoms (a, a+1, b, b+1) from LDS coords.
__device__ __forceinline__ float wr_val(const float4* __restrict__ xs4, int a, int b) {
    float4 q0 = xs4[a];
    float4 q1 = xs4[a + 1];
    float4 q2 = xs4[b];
    float4 q3 = xs4[b + 1];
    F3 p0 = {q0.x, q0.y, q0.z};
    F3 p1 = {q1.x, q1.y, q1.z};
    F3 p2 = {q2.x, q2.y, q2.z};
    F3 p3 = {q3.x, q3.y, q3.z};

    // Normalization of displacements cancels in normalized crosses and in the sign term.
    F3 d0 = f3sub(p2, p0), d1 = f3sub(p3, p0), d2 = f3sub(p2, p1), d3 = f3sub(p3, p1);

    F3 c0 = f3cross(d0, d1);
    F3 c1 = f3cross(d1, d3);
    F3 c2 = f3cross(d3, d2);
    F3 c3 = f3cross(d2, d0);

    float r0 = rsqrtf(f3dot(c0, c0));
    float r1 = rsqrtf(f3dot(c1, c1));
    float r2 = rsqrtf(f3dot(c2, c2));
    float r3 = rsqrtf(f3dot(c3, c3));

    float t01 = fminf(1.f, fmaxf(-1.f, f3dot(c0, c1) * (r0 * r1)));
    float t12 = fminf(1.f, fmaxf(-1.f, f3dot(c1, c2) * (r1 * r2)));
    float t23 = fminf(1.f, fmaxf(-1.f, f3dot(c2, c3) * (r2 * r3)));
    float t30 = fminf(1.f, fmaxf(-1.f, f3dot(c3, c0) * (r3 * r0)));

    float omega = fast_asinf(t01) + fast_asinf(t12) + fast_asinf(t23) + fast_asinf(t30);

    F3 e = f3cross(f3sub(p3, p2), f3sub(p1, p0));
    float sv = f3dot(e, d0);
    float sgn = (sv > 0.f) ? 1.f : ((sv < 0.f) ? -1.f : 0.f);

    return omega * sgn * 0.15915494309189535f;  // 1/(2*pi)
}

// One block per (upper-triangle tile pair, batch). Computes a 32x32 output tile,
// writes it and its transpose fully coalesced (zeros included -> no memset pass).
__global__ __launch_bounds__(256) void writhe_tile(const float* __restrict__ x,
                                                   float* __restrict__ out) {
    __shared__ float4 xs4[N];  // padded to 16B stride: point loads are ds_read_b128
    __shared__ float ts[TILE][TILE + 1];

    const int batch = blockIdx.y;
    const float* xb = x + (size_t)batch * (N * 3);
    for (int i = threadIdx.x; i < N; i += blockDim.x) {
        xs4[i] = make_float4(xb[3 * i], xb[3 * i + 1], xb[3 * i + 2], 0.f);
    }

    // Map blockIdx.x -> (ti, tj), ti <= tj, among 16x16 tiles (136 pairs).
    int p = blockIdx.x;
    int ti = 0;
    while (p >= (N / TILE) - ti) { p -= (N / TILE) - ti; ++ti; }
    const int tj = ti + p;

    __syncthreads();

    const int c = threadIdx.x & 31;
    const int r0 = threadIdx.x >> 5;
    const bool diag = (ti == tj);

    float* ob = out + (size_t)batch * (N * N);

#pragma unroll
    for (int k = 0; k < 4; ++k) {
        const int r = r0 + 8 * k;
        const int gi = ti * TILE + r;
        const int gj = tj * TILE + c;
        const int lo = min(gi, gj), hi = max(gi, gj);
        bool valid;
        int a, b;
        if (lo == 0) { valid = (hi >= 2) && (hi <= 510); a = 0; b = hi; }
        else         { valid = (hi >= lo + 2);           a = lo - 1; b = hi - 1; }
        float v = 0.f;
        if (valid) v = wr_val(xs4, a, b);
        ob[(size_t)gi * N + gj] = v;
        if (!diag) ts[r][c] = v;
    }

    if (!diag) {
        __syncthreads();
#pragma unroll
        for (int k = 0; k < 4; ++k) {
            const int r = r0 + 8 * k;
            ob[(size_t)(tj * TILE + r) * N + (ti * TILE + c)] = ts[c][r];
        }
    }
}

extern "C" void kernel_launch(void* const* d_in, const int* in_sizes, int n_in,
                              void* d_out, int out_size, void* d_ws, size_t ws_size,
                              hipStream_t stream) {
    const float* x = (const float*)d_in[0];
    float* out = (float*)d_out;
    const int B = in_sizes[0] / (N * 3);

    const int ntiles = N / TILE;                   // 16
    const int npairs = ntiles * (ntiles + 1) / 2;  // 136

    dim3 block(256);
    dim3 grid(npairs, B);
    writhe_tile<<<grid, block, 0, stream>>>(x, out);
}